// Round 7
// baseline (239.671 us; speedup 1.0000x reference)
//
#include <hip/hip_runtime.h>
#include <math.h>

// MoE router: X[8192,4096] fp32 @ W^T -> logits[8192,64] -> top2 softmax scatter.
// d_out = probs[8192*64] ++ routing_map[8192*64] (floats).
// ws: part [8][8192][64] fp32 (16MB). Wt (W^T, 1MB) staged in d_out scratch.
//
// R1: lane=token raw X reads -> 4x overfetch. Fixed via LDS staging.
// R2: 96us. lane=token + SMEM W: per-k lgkmcnt(0) drain, duty 30%.
// R3 FAILED: 2 tokens/lane -> ~170 live VGPRs -> scratch. acc<=64.
// R4 FAILED: W via per-j ds_read_b128 broadcast -> DS-instr flood (22%).
// R5: 8x8 reg-tile, x+w via LDS. 92us, VALUBusy 41%.
// R6: +1 wave/SIMD: ZERO gain -> pinned quantity is per-CU, not per-wave.
// R7/R8 FAILED: acc[64]+64-wide W operand loses regalloc -> scratch storm.
// R9: dist-2 SWP of frag loads: NULL (94us, 43.5%) -> not in-wave latency.
//     Triangulation: per-CU DS pipe is the wall. Broadcast b128 (~24cy, only
//     128B useful) x 256/chunk/CU + 128 b32 writes ~= 7150cy = chunk wall.
// R10: W off DS -> VMEM. wtrans (R7, proven) makes k-major Wt in d_out
//     scratch; w-frags via global dist-4 reg pipeline (k%4 const under
//     unroll; 512 FMA-cyc >> ~225cy L2 lat; Wt in every XCD L2). x stays
//     LDS (dist-2). DS/CU halves -> FMA pipe critical. ~155 VGPR, no spill.
//     Predict VALUBusy 65-85%, logits 42-58us.

#define HDIM 4096
#define NEXP 64
#define NTOK 8192
#define HG 8
#define HSLAB (HDIM / HG)   // 512 k per block
#define KK 16               // k per staged chunk
#define NCH (HSLAB / KK)    // 32 chunks
#define TPBK 64             // tokens per block (wave)
#define XS 68               // LDS row stride (floats)

// ---------------- kernel 0: W[64][4096] -> Wt[4096][64] ----------------
__global__ __launch_bounds__(64) void wtrans_kernel(
        const float* __restrict__ W, float* __restrict__ Wt) {
    __shared__ float t[64][65];
    const int kb = blockIdx.x * 64;
    const int lane = threadIdx.x;          // = expert e
    #pragma unroll
    for (int q = 0; q < 16; ++q) {
        float4 v = *reinterpret_cast<const float4*>(W + (size_t)lane * HDIM + kb + q * 4);
        t[lane][q * 4 + 0] = v.x; t[lane][q * 4 + 1] = v.y;
        t[lane][q * 4 + 2] = v.z; t[lane][q * 4 + 3] = v.w;
    }
    __syncthreads();
    #pragma unroll 4
    for (int k = 0; k < 64; ++k)
        Wt[(size_t)(kb + k) * NEXP + lane] = t[lane][k];
}

// ---------------- kernel 1: partial logits ----------------
__global__ __launch_bounds__(64) void logits_kernel(
        const float* __restrict__ X, const float* __restrict__ Wt,
        float* __restrict__ part) {
    const int tg   = blockIdx.x >> 3;   // 0..127
    const int hg   = blockIdx.x & 7;    // 0..7
    const int lane = threadIdx.x;       // 0..63
    const int tr   = lane >> 3;         // token-row group 0..7
    const int ec   = lane & 7;          // expert-col group 0..7

    __shared__ __align__(16) float xs[KK * XS];   // 4352 B (x tile only)

    const int token0 = tg * TPBK;
    const int hbase  = hg * HSLAB;

    const int r4 = lane >> 2;           // 0..15
    const int sl = lane & 3;            // 0..3

    float acc[8][8];
    #pragma unroll
    for (int i = 0; i < 8; ++i)
        #pragma unroll
        for (int j = 0; j < 8; ++j) acc[i][j] = 0.f;

    const float* Xb = X + (size_t)token0 * HDIM + hbase;
    const float* Wb = Wt + (size_t)hbase * NEXP + ec * 8;   // k-major rows

    float4 pfx[4];
    // ---- prologue: load + scatter x chunk 0 ----
    #pragma unroll
    for (int p = 0; p < 4; ++p) {
        int row = p * 16 + r4;
        pfx[p] = *reinterpret_cast<const float4*>(Xb + (size_t)row * HDIM + sl * 4);
    }
    #pragma unroll
    for (int p = 0; p < 4; ++p) {
        int row = p * 16 + r4;
        xs[(sl * 4 + 0) * XS + row] = pfx[p].x;
        xs[(sl * 4 + 1) * XS + row] = pfx[p].y;
        xs[(sl * 4 + 2) * XS + row] = pfx[p].z;
        xs[(sl * 4 + 3) * XS + row] = pfx[p].w;
    }
    __syncthreads();

    // ---- prime w pipeline: flat k = 0..3 (distance-4, 4 slots) ----
    float4 fw0[4], fw1[4];
    #pragma unroll
    for (int k = 0; k < 4; ++k) {
        const float4* wr = reinterpret_cast<const float4*>(Wb + (size_t)k * NEXP);
        fw0[k] = wr[0]; fw1[k] = wr[1];
    }
    // ---- prime x pipeline: chunk-local k = 0,1 (distance-2, 2 slots) ----
    float4 fx0[2], fx1[2];
    #pragma unroll
    for (int k = 0; k < 2; ++k) {
        const float4* xr = reinterpret_cast<const float4*>(xs + k * XS + tr * 8);
        fx0[k] = xr[0]; fx1[k] = xr[1];
    }

    for (int c = 0; c < NCH; ++c) {
        if (c + 1 < NCH) {              // global prefetch of next x chunk
            const int off = (c + 1) * KK;
            #pragma unroll
            for (int p = 0; p < 4; ++p) {
                int row = p * 16 + r4;
                pfx[p] = *reinterpret_cast<const float4*>(
                    Xb + (size_t)row * HDIM + off + sl * 4);
            }
        }
        // ---- compute: per k, 2 LDS b128 (x) + 2 VMEM b128 (w, dist-4) ----
        #pragma unroll
        for (int k = 0; k < KK; ++k) {
            // consume (slot indices compile-time after unroll)
            float xv[8] = {fx0[k % 2].x, fx0[k % 2].y, fx0[k % 2].z, fx0[k % 2].w,
                           fx1[k % 2].x, fx1[k % 2].y, fx1[k % 2].z, fx1[k % 2].w};
            float wv[8] = {fw0[k % 4].x, fw0[k % 4].y, fw0[k % 4].z, fw0[k % 4].w,
                           fw1[k % 4].x, fw1[k % 4].y, fw1[k % 4].z, fw1[k % 4].w};
            #pragma unroll
            for (int i = 0; i < 8; ++i)
                #pragma unroll
                for (int j = 0; j < 8; ++j)
                    acc[i][j] = fmaf(xv[i], wv[j], acc[i][j]);
            // refill w slot k%4 with flat k+4 (clamped; uniform scalar)
            {
                int kn = c * KK + k + 4;
                if (kn >= HSLAB) kn = HSLAB - 1;
                const float4* wr = reinterpret_cast<const float4*>(Wb + (size_t)kn * NEXP);
                fw0[k % 4] = wr[0]; fw1[k % 4] = wr[1];
            }
            // refill x slot k%2 with chunk-local k+2
            if (k + 2 < KK) {
                const float4* xr = reinterpret_cast<const float4*>(xs + (k + 2) * XS + tr * 8);
                fx0[k % 2] = xr[0]; fx1[k % 2] = xr[1];
            }
        }
        __syncthreads();
        if (c + 1 < NCH) {              // commit prefetched x chunk
            #pragma unroll
            for (int p = 0; p < 4; ++p) {
                int row = p * 16 + r4;
                xs[(sl * 4 + 0) * XS + row] = pfx[p].x;
                xs[(sl * 4 + 1) * XS + row] = pfx[p].y;
                xs[(sl * 4 + 2) * XS + row] = pfx[p].z;
                xs[(sl * 4 + 3) * XS + row] = pfx[p].w;
            }
        }
        __syncthreads();
        if (c + 1 < NCH) {              // re-prime x slots for next chunk
            #pragma unroll
            for (int k = 0; k < 2; ++k) {
                const float4* xr = reinterpret_cast<const float4*>(xs + k * XS + tr * 8);
                fx0[k] = xr[0]; fx1[k] = xr[1];
            }
        }
    }

    // ---- epilogue: per lane 8 tokens x 8 consecutive experts ----
    float* dst = part + ((size_t)hg * NTOK + token0) * NEXP;
    #pragma unroll
    for (int i = 0; i < 8; ++i) {
        int t = tr * 8 + i;
        *reinterpret_cast<float4*>(dst + (size_t)t * NEXP + ec * 8) =
            make_float4(acc[i][0], acc[i][1], acc[i][2], acc[i][3]);
        *reinterpret_cast<float4*>(dst + (size_t)t * NEXP + ec * 8 + 4) =
            make_float4(acc[i][4], acc[i][5], acc[i][6], acc[i][7]);
    }
}

// ---------------- kernel 2: reduce HG partials, top-2 softmax, scatter ----------------
__global__ __launch_bounds__(256) void topk_kernel(
        const float* __restrict__ part, float* __restrict__ probs,
        float* __restrict__ rmap) {
    const int wave = threadIdx.x >> 6;
    const int lane = threadIdx.x & 63;       // lane = expert
    const int token = blockIdx.x * 4 + wave;

    const float* p = part + (size_t)token * NEXP + lane;
    float v = 0.f;
    #pragma unroll
    for (int hg = 0; hg < HG; ++hg) v += p[(size_t)hg * NTOK * NEXP];

    // top-1 (lower index wins ties, like lax.top_k)
    float m1 = v; int i1 = lane;
    #pragma unroll
    for (int s = 32; s > 0; s >>= 1) {
        float om = __shfl_xor(m1, s, 64);
        int   oi = __shfl_xor(i1, s, 64);
        if (om > m1 || (om == m1 && oi < i1)) { m1 = om; i1 = oi; }
    }
    // top-2: exclude i1
    float vx = (lane == i1) ? -INFINITY : v;
    float m2 = vx; int i2 = lane;
    #pragma unroll
    for (int s = 32; s > 0; s >>= 1) {
        float om = __shfl_xor(m2, s, 64);
        int   oi = __shfl_xor(i2, s, 64);
        if (om > m2 || (om == m2 && oi < i2)) { m2 = om; i2 = oi; }
    }

    float e2 = expf(m2 - m1);
    float p1 = 1.f / (1.f + e2);
    float p2 = 1.f - p1;

    float prob = (lane == i1) ? p1 : ((lane == i2) ? p2 : 0.f);
    float flag = (lane == i1 || lane == i2) ? 1.f : 0.f;
    probs[(size_t)token * NEXP + lane] = prob;
    rmap [(size_t)token * NEXP + lane] = flag;
}

extern "C" void kernel_launch(void* const* d_in, const int* in_sizes, int n_in,
                              void* d_out, int out_size, void* d_ws, size_t ws_size,
                              hipStream_t stream) {
    const float* X = (const float*)d_in[0];   // [8192,4096]
    const float* W = (const float*)d_in[1];   // [64,4096]
    float* out  = (float*)d_out;
    float* part = (float*)d_ws;               // [8][8192][64] floats = 16MB
    float* Wt   = out;                        // 1MB scratch in d_out; logits
                                              // reads it before topk overwrites.

    wtrans_kernel<<<HDIM / 64, 64, 0, stream>>>(W, Wt);
    logits_kernel<<<128 * HG, 64, 0, stream>>>(X, Wt, part);
    topk_kernel<<<NTOK / 4, 256, 0, stream>>>(part, out, out + (size_t)NTOK * NEXP);
}